// Round 1
// 1467.851 us; speedup vs baseline: 1.1998x; 1.1998x over previous
//
#include <hip/hip_runtime.h>
#include <hip/hip_bf16.h>

// Problem constants (B=1)
#define S_LEN 4096
#define HID 2048
#define NH 16
#define NKV 4
#define HD 128        // D
#define MSK 32        // M (sketch dim)
#define KTOP 8
#define NBLK 64       // S/BLK
#define NEGV -1000000000.0f
#define SENT -3.0e38f

typedef __hip_bfloat16 bf16;
typedef __attribute__((ext_vector_type(8))) short short8;   // 8 bf16 (4 VGPR)
typedef __attribute__((ext_vector_type(4))) float f32x4;

// EMPIRICAL (R1-R9): inputs fp32, output fp32. Selection (sketch->topk) needs
// near-fp32 precision; R10 moves projection to MFMA via bf16x3 emulation
// (hi*hi + hi*lo + lo*hi, fp32 accum) ~= 2^-16.5 relative -- far tighter than
// plain bf16 (2^-9, known-bad), close to fp32 accumulation (2^-18.5).

__device__ __forceinline__ unsigned short f2b(float v) {
    __hip_bfloat16 h = __float2bfloat16(v);
    return *reinterpret_cast<unsigned short*>(&h);
}
__device__ __forceinline__ float b2f(unsigned short u) {
    return __bfloat162float(*reinterpret_cast<__hip_bfloat16*>(&u));
}
__device__ __forceinline__ void stc(bf16* p, float v) { *p = __float2bfloat16(v); }
__device__ __forceinline__ void stc(float* p, float v) { *p = v; }

// ---------------------------------------------------------------------------
// FUSED projection + RoPE + block-sketch, v3 (MFMA bf16x3):
// One block = 128 rows x 128 cols (one head), 4 waves x (32 rows x 128 cols),
// mfma_f32_16x16x32_bf16, 3 products per tile (hi*hi + hi*lo + lo*hi).
// RoPE partner col^64 is acc tile nt^4, SAME lane -> register-only rotation.
// Sketch: row-sum accumulators (reg + shfl), then 128x32 matvec on 64 thr.
// ---------------------------------------------------------------------------
__global__ __launch_bounds__(256) void proj_rope_sketch(
    const float* __restrict__ A, const float* __restrict__ W,
    const int* __restrict__ pos_ids, const float* __restrict__ H,
    bf16* __restrict__ Xout, float* __restrict__ Sout,
    int nheads, int r0, int xbase) {
    const int h = blockIdx.x;
    const int m0g = r0 + blockIdx.y * 128;     // global row base (128 rows)
    const int m0x = m0g - xbase;
    const int Nd = nheads * HD;
    const int t = threadIdx.x;
    const int w = t >> 6, L = t & 63;
    const int lm = L & 15, lq = L >> 4;

    // LDS: [row][k] hi/lo for A, [col][k] hi/lo for W; stride 40 shorts (80B)
    // breaks the 64B-stride bank alias (2-way residual = free, m136).
    __shared__ __align__(16) unsigned short pAh[128][40];
    __shared__ __align__(16) unsigned short pAl[128][40];
    __shared__ __align__(16) unsigned short pWh[128][40];
    __shared__ __align__(16) unsigned short pWl[128][40];
    __shared__ float red[4][128];

    f32x4 acc[2][8];
#pragma unroll
    for (int mt = 0; mt < 2; mt++)
#pragma unroll
        for (int nt = 0; nt < 8; nt++) acc[mt][nt] = (f32x4){0.f, 0.f, 0.f, 0.f};

    for (int k0 = 0; k0 < HID; k0 += 32) {
        __syncthreads();
        // A tile: 128 rows x 32 k (float4 coalesced), split fp32 -> bf16 hi/lo
#pragma unroll
        for (int i = 0; i < 4; i++) {
            const int idx = t + i * 256;           // 1024 float4
            const int row = idx >> 3, f4 = idx & 7;
            const float4 v = *(const float4*)&A[(size_t)(m0g + row) * HID + k0 + f4 * 4];
            ushort4 uh, ul;
            uh.x = f2b(v.x); ul.x = f2b(v.x - b2f(uh.x));
            uh.y = f2b(v.y); ul.y = f2b(v.y - b2f(uh.y));
            uh.z = f2b(v.z); ul.z = f2b(v.z - b2f(uh.z));
            uh.w = f2b(v.w); ul.w = f2b(v.w - b2f(uh.w));
            *(ushort4*)&pAh[row][f4 * 4] = uh;
            *(ushort4*)&pAl[row][f4 * 4] = ul;
        }
        // W tile: 32 k x 128 n, staged k-major per column (aligned 16B LDS
        // writes, no transpose scatter). Global: 2 x 128B segments per instr.
        {
            const int wcol = t >> 1, wk0 = (t & 1) * 16;
            const float* wp = &W[(size_t)(k0 + wk0) * Nd + h * HD + wcol];
            alignas(16) unsigned short hh[16];
            alignas(16) unsigned short ll[16];
#pragma unroll
            for (int u = 0; u < 16; u++) {
                const float x = wp[(size_t)u * Nd];
                hh[u] = f2b(x);
                ll[u] = f2b(x - b2f(hh[u]));
            }
            *(uint4*)&pWh[wcol][wk0 + 0] = *(const uint4*)&hh[0];
            *(uint4*)&pWh[wcol][wk0 + 8] = *(const uint4*)&hh[8];
            *(uint4*)&pWl[wcol][wk0 + 0] = *(const uint4*)&ll[0];
            *(uint4*)&pWl[wcol][wk0 + 8] = *(const uint4*)&ll[8];
        }
        __syncthreads();
        // fragments: A[row=lm][k=lq*8+j], B[col=lm][k=lq*8+j]
        short8 ah[2], al[2];
#pragma unroll
        for (int mt = 0; mt < 2; mt++) {
            ah[mt] = *(const short8*)&pAh[w * 32 + mt * 16 + lm][lq * 8];
            al[mt] = *(const short8*)&pAl[w * 32 + mt * 16 + lm][lq * 8];
        }
#pragma unroll
        for (int nt = 0; nt < 8; nt++) {
            const short8 bh = *(const short8*)&pWh[nt * 16 + lm][lq * 8];
            const short8 bl = *(const short8*)&pWl[nt * 16 + lm][lq * 8];
#pragma unroll
            for (int mt = 0; mt < 2; mt++) {
                acc[mt][nt] = __builtin_amdgcn_mfma_f32_16x16x32_bf16(ah[mt], bh, acc[mt][nt], 0, 0, 0);
                acc[mt][nt] = __builtin_amdgcn_mfma_f32_16x16x32_bf16(ah[mt], bl, acc[mt][nt], 0, 0, 0);
                acc[mt][nt] = __builtin_amdgcn_mfma_f32_16x16x32_bf16(al[mt], bh, acc[mt][nt], 0, 0, 0);
            }
        }
    }

    // ---- RoPE (register-only; partner col^64 = tile nt^4, same lane) ----
    float invf[4];
#pragma unroll
    for (int c4 = 0; c4 < 4; c4++) {
        const int jj = c4 * 16 + lm;              // col & 63
        invf[c4] = 1.0f / powf(10000.0f, (float)jj * (1.0f / 64.0f));
    }
#pragma unroll
    for (int mt = 0; mt < 2; mt++) {
        const int rbase = w * 32 + mt * 16 + lq * 4;
#pragma unroll
        for (int rr = 0; rr < 4; rr++) {
            const float p = (float)pos_ids[m0g + rbase + rr];
#pragma unroll
            for (int c4 = 0; c4 < 4; c4++) {
                const float fr = p * invf[c4];
                float sv, cv;
                sincosf(fr, &sv, &cv);
                const float x1 = acc[mt][c4][rr];      // col < 64
                const float x2 = acc[mt][c4 + 4][rr];  // col + 64
                acc[mt][c4][rr]     = x1 * cv - x2 * sv;
                acc[mt][c4 + 4][rr] = x2 * cv + x1 * sv;
            }
        }
    }

    // ---- bf16 store + per-column row-sums for the sketch ----
    float cs[8];
#pragma unroll
    for (int nt = 0; nt < 8; nt++) cs[nt] = 0.f;
#pragma unroll
    for (int mt = 0; mt < 2; mt++) {
        const int rbase = w * 32 + mt * 16 + lq * 4;
#pragma unroll
        for (int rr = 0; rr < 4; rr++) {
            bf16* dst = &Xout[(size_t)(m0x + rbase + rr) * Nd + h * HD + lm];
#pragma unroll
            for (int nt = 0; nt < 8; nt++) {
                const float v = acc[mt][nt][rr];
                dst[nt * 16] = __float2bfloat16(v);
                cs[nt] += v;
            }
        }
    }
    // reduce across the 4 quads (rows) of the wave
#pragma unroll
    for (int nt = 0; nt < 8; nt++) {
        cs[nt] += __shfl_xor(cs[nt], 16);
        cs[nt] += __shfl_xor(cs[nt], 32);
    }
    if (lq == 0) {
#pragma unroll
        for (int nt = 0; nt < 8; nt++) red[w][nt * 16 + lm] = cs[nt];
    }
    __syncthreads();
    // Sketch matvec: S[b][m] = (1/64) * sum_d colsum_b[d] * H[d][m]
    if (t < 64) {
        const int b = t >> 5, m = t & 31;
        float s = 0.f;
        for (int d = 0; d < 128; d++)
            s += (red[b * 2][d] + red[b * 2 + 1][d]) * H[d * MSK + m];
        Sout[((size_t)h * NBLK + (m0g >> 6) + b) * MSK + m] = s * (1.0f / 64.0f);
    }
}

// ---------------------------------------------------------------------------
// MFMA bf16 GEMM: C[cRow0+m, n] = A[m,:] @ W[:,n]. 64x64 tile, 4 waves,
// mfma_f32_16x16x32_bf16. A fp32 (convert) or bf16 (direct); W fp32->bf16.
// ---------------------------------------------------------------------------
__device__ __forceinline__ void stage8(const float* p, unsigned short* dst) {
    const float4 a = *(const float4*)p;
    const float4 b = *(const float4*)(p + 4);
    ushort4 u0; u0.x = f2b(a.x); u0.y = f2b(a.y); u0.z = f2b(a.z); u0.w = f2b(a.w);
    ushort4 u1; u1.x = f2b(b.x); u1.y = f2b(b.y); u1.z = f2b(b.z); u1.w = f2b(b.w);
    *(ushort4*)dst = u0; *(ushort4*)(dst + 4) = u1;
}
__device__ __forceinline__ void stage8(const bf16* p, unsigned short* dst) {
    *(uint4*)dst = *(const uint4*)p;
}

template <typename AT, typename CT>
__global__ __launch_bounds__(256) void gemm_mfma(const AT* __restrict__ A,
                                                 const float* __restrict__ W,
                                                 CT* __restrict__ C,
                                                 int Ndim, int Kdim, int cRow0) {
    __shared__ unsigned short Al[64][40];   // [m][k], stride 80B (16B-aligned)
    __shared__ unsigned short Wl[64][40];   // [n][k] (transposed in staging)
    const int n0 = blockIdx.x * 64, m0 = blockIdx.y * 64;
    const int t = threadIdx.x;
    const int w = t >> 6, L = t & 63;
    const int lm = L & 15, lq = L >> 4;
    f32x4 acc[4];
#pragma unroll
    for (int nt = 0; nt < 4; nt++) acc[nt] = (f32x4){0.f, 0.f, 0.f, 0.f};

    for (int k0 = 0; k0 < Kdim; k0 += 32) {
        __syncthreads();
        {   // A: 64 rows x 32 k; thread -> (row = t>>2, 8-el chunk = t&3)
            int row = t >> 2, c8 = t & 3;
            stage8(&A[(size_t)(m0 + row) * Kdim + k0 + c8 * 8], &Al[row][c8 * 8]);
        }
        {   // W: 32 k x 64 n, transposed into Wl[n][k]
            int kk = t >> 3, n8 = (t & 7) * 8;
            const float4 a = *(const float4*)&W[(size_t)(k0 + kk) * Ndim + n0 + n8];
            const float4 b = *(const float4*)&W[(size_t)(k0 + kk) * Ndim + n0 + n8 + 4];
            Wl[n8 + 0][kk] = f2b(a.x); Wl[n8 + 1][kk] = f2b(a.y);
            Wl[n8 + 2][kk] = f2b(a.z); Wl[n8 + 3][kk] = f2b(a.w);
            Wl[n8 + 4][kk] = f2b(b.x); Wl[n8 + 5][kk] = f2b(b.y);
            Wl[n8 + 6][kk] = f2b(b.z); Wl[n8 + 7][kk] = f2b(b.w);
        }
        __syncthreads();
        short8 av = *(const short8*)&Al[w * 16 + lm][lq * 8];
#pragma unroll
        for (int nt = 0; nt < 4; nt++) {
            short8 bv = *(const short8*)&Wl[nt * 16 + lm][lq * 8];
            acc[nt] = __builtin_amdgcn_mfma_f32_16x16x32_bf16(av, bv, acc[nt], 0, 0, 0);
        }
    }
#pragma unroll
    for (int nt = 0; nt < 4; nt++)
#pragma unroll
        for (int r = 0; r < 4; r++) {
            int row = w * 16 + lq * 4 + r, col = nt * 16 + lm;
            stc(&C[(size_t)(cRow0 + m0 + row) * Ndim + n0 + col], acc[nt][r]);
        }
}

// ---------------------------------------------------------------------------
// Block scores + top-8 for q-blocks i = i0 + bx. Tie-break = lowest index.
// ---------------------------------------------------------------------------
__global__ __launch_bounds__(64) void topk_kernel(const float* __restrict__ Sq,
                                                  const float* __restrict__ Sk,
                                                  int* __restrict__ topk, int i0) {
    const int i = i0 + blockIdx.x, h = blockIdx.y, kv = h >> 2;
    const int j = threadIdx.x;
    __shared__ float vals[64];
    float v;
    if (j > i) v = NEGV;
    else if (j == i) v = 1e9f;
    else {
        v = 0.f;
        const float* sq = Sq + ((size_t)h * NBLK + i) * MSK;
        const float* sk = Sk + ((size_t)kv * NBLK + j) * MSK;
        for (int m = 0; m < MSK; m++) v += sq[m] * sk[m];
    }
    vals[j] = v;
    __syncthreads();
    if (j == 0) {
        for (int kk = 0; kk < KTOP; kk++) {
            float best = SENT; int bi = 0;
            for (int jj = 0; jj < 64; jj++)
                if (vals[jj] > best) { best = vals[jj]; bi = jj; }
            vals[bi] = SENT;
            topk[((size_t)h * NBLK + i) * KTOP + kk] = bi;
        }
    }
}

// ---------------------------------------------------------------------------
// Sparse attention, online softmax, rows [r0, r0+CHrows). q rows are
// (global - qbase) in qf. Writes attn_c chunk-local (rows - r0).
// ---------------------------------------------------------------------------
__global__ __launch_bounds__(256) void attn_kernel(const bf16* __restrict__ qf,
                                                   const bf16* __restrict__ kf,
                                                   const bf16* __restrict__ vf,
                                                   const int* __restrict__ topk,
                                                   bf16* __restrict__ attn_c,
                                                   int r0, int qbase) {
    const int qbg = (r0 >> 6) + blockIdx.x;
    const int h = blockIdx.y, half = blockIdx.z;
    const int kvh = h >> 2;
    const int t = threadIdx.x;
    const int r = t & 31, g = t >> 5;
    __shared__ float Qs[32][129];
    __shared__ float KVs[64][129];
    __shared__ float Ss[32][65];
    __shared__ float mL[32], lL[32], aL[32];
    const int qrow0 = qbg * 64 + half * 32;

#pragma unroll
    for (int i = 0; i < 2; i++) {   // 32x128 bf16 = 512 uint4
        int idx = t + i * 256;
        int rr = idx >> 4, c8 = idx & 15;
        uint4 raw = *(const uint4*)&qf[(size_t)(qrow0 - qbase + rr) * (NH * HD) + h * HD + c8 * 8];
        const unsigned short* pu = (const unsigned short*)&raw;
#pragma unroll
        for (int j = 0; j < 8; j++)
            Qs[rr][c8 * 8 + j] = b2f(pu[j]) * 0.08838834764831845f;
    }
    if (t < 32) { mL[t] = -1.0e30f; lL[t] = 0.f; }
    float O[16];
#pragma unroll
    for (int c = 0; c < 16; c++) O[c] = 0.f;
    const int c0 = g * 16;
    const int* sel = topk + ((size_t)h * NBLK + qbg) * KTOP;

    for (int kb = 0; kb < KTOP; kb++) {
        const int blk = sel[kb] & 63;
        __syncthreads();   // (A)
#pragma unroll
        for (int i = 0; i < 4; i++) {   // 64x128 bf16 = 1024 uint4
            int idx = t + i * 256;
            int rr = idx >> 4, c8 = idx & 15;
            uint4 raw = *(const uint4*)&kf[(size_t)(blk * 64 + rr) * (NKV * HD) + kvh * HD + c8 * 8];
            const unsigned short* pu = (const unsigned short*)&raw;
#pragma unroll
            for (int j = 0; j < 8; j++) KVs[rr][c8 * 8 + j] = b2f(pu[j]);
        }
        __syncthreads();   // (B)
        float sc[8];
#pragma unroll
        for (int jj = 0; jj < 8; jj++) sc[jj] = 0.f;
        for (int d = 0; d < 128; d++) {
            float qv = Qs[r][d];
#pragma unroll
            for (int jj = 0; jj < 8; jj++) sc[jj] += qv * KVs[g * 8 + jj][d];
        }
        const int qpos = qrow0 + r;
#pragma unroll
        for (int jj = 0; jj < 8; jj++) {
            int j = g * 8 + jj;
            int kpos = blk * 64 + j;
            Ss[r][j] = (kpos <= qpos) ? sc[jj] : NEGV;
        }
        __syncthreads();   // (C)
#pragma unroll
        for (int i = 0; i < 4; i++) {   // stage V over K
            int idx = t + i * 256;
            int rr = idx >> 4, c8 = idx & 15;
            uint4 raw = *(const uint4*)&vf[(size_t)(blk * 64 + rr) * (NKV * HD) + kvh * HD + c8 * 8];
            const unsigned short* pu = (const unsigned short*)&raw;
#pragma unroll
            for (int j = 0; j < 8; j++) KVs[rr][c8 * 8 + j] = b2f(pu[j]);
        }
        if (t < 32) {
            const int row = t;
            float mb = SENT;
            for (int j = 0; j < 64; j++) mb = fmaxf(mb, Ss[row][j]);
            float mnew = fmaxf(mL[row], mb);
            float al = expf(mL[row] - mnew);
            float sum = 0.f;
            for (int j = 0; j < 64; j++) {
                float p = expf(Ss[row][j] - mnew);
                Ss[row][j] = p;
                sum += p;
            }
            lL[row] = lL[row] * al + sum;
            mL[row] = mnew;
            aL[row] = al;
        }
        __syncthreads();   // (D)
        float al = aL[r];
#pragma unroll
        for (int c = 0; c < 16; c++) O[c] *= al;
        for (int j = 0; j < 64; j++) {
            float p = Ss[r][j];
#pragma unroll
            for (int c = 0; c < 16; c++) O[c] += p * KVs[j][c0 + c];
        }
    }
    float inv_l = 1.0f / lL[r];
    bf16* dst = &attn_c[(size_t)(qrow0 - r0 + r) * (NH * HD) + h * HD + c0];
#pragma unroll
    for (int c4 = 0; c4 < 4; c4++) {
        ushort4 u;
        u.x = f2b(O[c4 * 4 + 0] * inv_l); u.y = f2b(O[c4 * 4 + 1] * inv_l);
        u.z = f2b(O[c4 * 4 + 2] * inv_l); u.w = f2b(O[c4 * 4 + 3] * inv_l);
        *(ushort4*)&dst[c4 * 4] = u;
    }
}

// ---------------------------------------------------------------------------
extern "C" void kernel_launch(void* const* d_in, const int* in_sizes, int n_in,
                              void* d_out, int out_size, void* d_ws, size_t ws_size,
                              hipStream_t stream) {
    const void *p_hid, *p_pos, *p_wq, *p_wk, *p_wv, *p_wo, *p_h;
    if (in_sizes[0] == 4096 && in_sizes[1] == 1048576) {
        p_h = d_in[0]; p_wk = d_in[1]; p_wo = d_in[2]; p_wq = d_in[3];
        p_wv = d_in[4]; p_hid = d_in[5]; p_pos = d_in[6];
    } else {
        p_hid = d_in[0]; p_pos = d_in[1]; p_wq = d_in[2]; p_wk = d_in[3];
        p_wv = d_in[4]; p_wo = d_in[5]; p_h = d_in[6];
    }
    const float* hidden = (const float*)p_hid;
    const int* pos_ids  = (const int*)p_pos;
    const float* Wq = (const float*)p_wq;
    const float* Wk = (const float*)p_wk;
    const float* Wv = (const float*)p_wv;
    const float* Wo = (const float*)p_wo;
    const float* Hsk = (const float*)p_h;
    float* out = (float*)d_out;

    // ws layout (bytes): Sq 131072 | Sk 32768 | topk 32768 | kf 4M | vf 4M |
    //   full: qf 16.78M | attn_c 4M  (total 29,556,736)
    //   fallback (proven 10.68MB): q_c 1M | attn_c 1M
    char* base = (char*)d_ws;
    float* Sq    = (float*)base;
    float* Sk    = (float*)(base + 131072);
    int*   topkb = (int*)(base + 163840);
    bf16*  kf    = (bf16*)(base + 196608);
    bf16*  vf    = (bf16*)(base + 196608 + 4194304);
    bf16*  qbuf  = (bf16*)(base + 196608 + 8388608);
    const size_t FULL_NEED = 29556736;
    const bool full = (ws_size >= FULL_NEED);

    // K projection+rope+sketch (full S, 128-row blocks), V projection (MFMA).
    proj_rope_sketch<<<dim3(NKV, S_LEN / 128), 256, 0, stream>>>(
        hidden, Wk, pos_ids, Hsk, kf, Sk, NKV, 0, 0);
    gemm_mfma<float, bf16><<<dim3((NKV * HD) / 64, S_LEN / 64), 256, 0, stream>>>(
        hidden, Wv, vf, NKV * HD, HID, 0);

    if (full) {
        bf16* attn_c = qbuf + (size_t)S_LEN * NH * HD;     // 4MB, CH=1024
        // Q proj (full S, one launch), topk (one launch)
        proj_rope_sketch<<<dim3(NH, S_LEN / 128), 256, 0, stream>>>(
            hidden, Wq, pos_ids, Hsk, qbuf, Sq, NH, 0, 0);
        topk_kernel<<<dim3(NBLK, NH), 64, 0, stream>>>(Sq, Sk, topkb, 0);
        for (int c = 0; c < 4; c++) {
            const int r0 = c * 1024;
            attn_kernel<<<dim3(16, NH, 2), 256, 0, stream>>>(
                qbuf, kf, vf, topkb, attn_c, r0, 0);
            gemm_mfma<bf16, float><<<dim3(HID / 64, 16), 256, 0, stream>>>(
                attn_c, Wo, out, HID, HID, r0);
        }
    } else {
        bf16* attn_c = qbuf + (size_t)256 * NH * HD;       // 1MB, CH=256
        for (int c = 0; c < 16; c++) {
            const int r0 = c * 256;
            proj_rope_sketch<<<dim3(NH, 2), 256, 0, stream>>>(
                hidden, Wq, pos_ids, Hsk, qbuf, Sq, NH, r0, r0);
            topk_kernel<<<dim3(4, NH), 64, 0, stream>>>(Sq, Sk, topkb, r0 >> 6);
            attn_kernel<<<dim3(4, NH, 2), 256, 0, stream>>>(
                qbuf, kf, vf, topkb, attn_c, r0, r0);
            gemm_mfma<bf16, float><<<dim3(HID / 64, 4), 256, 0, stream>>>(
                attn_c, Wo, out, HID, HID, r0);
        }
    }
}

// Round 2
// 1323.720 us; speedup vs baseline: 1.3304x; 1.1089x over previous
//
#include <hip/hip_runtime.h>
#include <hip/hip_bf16.h>

// Problem constants (B=1)
#define S_LEN 4096
#define HID 2048
#define NH 16
#define NKV 4
#define HD 128        // D
#define MSK 32        // M (sketch dim)
#define KTOP 8
#define NBLK 64       // S/BLK
#define NEGV -1000000000.0f
#define SENT -3.0e38f

typedef __hip_bfloat16 bf16;
typedef __attribute__((ext_vector_type(8))) short short8;   // 8 bf16 (4 VGPR)
typedef __attribute__((ext_vector_type(4))) float f32x4;

// EMPIRICAL (R1-R10): inputs fp32, output fp32. Selection (sketch->topk) needs
// near-fp32 precision: bf16x3 emulation (hi*hi + hi*lo + lo*hi, fp32 accum)
// ~= 2^-16.5 relative. V path needs only plain-bf16 precision (1 product).
// R11: Q/K/V projections merged into ONE launch (768 blocks, 3 blocks/CU) --
// previous split ran K proj at 0.5 blocks/CU and serialized three dispatches.

__device__ __forceinline__ unsigned short f2b(float v) {
    __hip_bfloat16 h = __float2bfloat16(v);
    return *reinterpret_cast<unsigned short*>(&h);
}
__device__ __forceinline__ float b2f(unsigned short u) {
    return __bfloat162float(*reinterpret_cast<__hip_bfloat16*>(&u));
}
__device__ __forceinline__ void stc(bf16* p, float v) { *p = __float2bfloat16(v); }
__device__ __forceinline__ void stc(float* p, float v) { *p = v; }

// ---------------------------------------------------------------------------
// FUSED Q/K/V projection + RoPE + block-sketch (MFMA bf16x3), one launch.
// blockIdx.x + u0 = unit: [0,16) Q head, [16,20) K head, [20,24) V head.
// One block = 128 rows x 128 cols, 4 waves x (32 rows x 128 cols),
// mfma_f32_16x16x32_bf16. Q/K: 3 products; V: 1 product (bf16 precision ok).
// RoPE partner col^64 is acc tile nt^4, SAME lane -> register-only rotation.
// Sketch: row-sum accumulators (reg + shfl), then 128x32 matvec on 64 thr.
// ---------------------------------------------------------------------------
__global__ __launch_bounds__(256, 3) void proj_rope_sketch(
    const float* __restrict__ A, const float* __restrict__ Wq,
    const float* __restrict__ Wk, const float* __restrict__ Wv,
    const int* __restrict__ pos_ids, const float* __restrict__ H,
    bf16* __restrict__ qf, bf16* __restrict__ kf, bf16* __restrict__ vf,
    float* __restrict__ Sq, float* __restrict__ Sk,
    int u0, int r0, int xbase) {
    const int u = blockIdx.x + u0;
    const bool isQ = (u < 16);
    const bool isV = (u >= 20);
    const bool np3 = !isV;                 // Q/K: 3 products, V: 1
    const int h = isQ ? u : (isV ? (u - 20) : (u - 16));
    const float* __restrict__ W = isQ ? Wq : (isV ? Wv : Wk);
    const int Nd = isQ ? (NH * HD) : (NKV * HD);
    bf16* __restrict__ Xout = isQ ? qf : (isV ? vf : kf);
    float* __restrict__ Sout = isQ ? Sq : Sk;

    const int m0g = r0 + blockIdx.y * 128;     // global row base (128 rows)
    const int m0x = isQ ? (m0g - xbase) : m0g; // only qf is chunk-local
    const int t = threadIdx.x;
    const int w = t >> 6, L = t & 63;
    const int lm = L & 15, lq = L >> 4;

    // LDS: [row][k] hi/lo for A, [col][k] hi/lo for W; stride 40 shorts (80B).
    __shared__ __align__(16) unsigned short pAh[128][40];
    __shared__ __align__(16) unsigned short pAl[128][40];
    __shared__ __align__(16) unsigned short pWh[128][40];
    __shared__ __align__(16) unsigned short pWl[128][40];
    __shared__ float red[4][128];

    f32x4 acc[2][8];
#pragma unroll
    for (int mt = 0; mt < 2; mt++)
#pragma unroll
        for (int nt = 0; nt < 8; nt++) acc[mt][nt] = (f32x4){0.f, 0.f, 0.f, 0.f};

    for (int k0 = 0; k0 < HID; k0 += 32) {
        __syncthreads();
        // A tile: 128 rows x 32 k (float4 coalesced), split fp32 -> bf16 hi/lo
#pragma unroll
        for (int i = 0; i < 4; i++) {
            const int idx = t + i * 256;           // 1024 float4
            const int row = idx >> 3, f4 = idx & 7;
            const float4 v = *(const float4*)&A[(size_t)(m0g + row) * HID + k0 + f4 * 4];
            ushort4 uh;
            uh.x = f2b(v.x); uh.y = f2b(v.y); uh.z = f2b(v.z); uh.w = f2b(v.w);
            *(ushort4*)&pAh[row][f4 * 4] = uh;
            if (np3) {
                ushort4 ul;
                ul.x = f2b(v.x - b2f(uh.x)); ul.y = f2b(v.y - b2f(uh.y));
                ul.z = f2b(v.z - b2f(uh.z)); ul.w = f2b(v.w - b2f(uh.w));
                *(ushort4*)&pAl[row][f4 * 4] = ul;
            }
        }
        // W tile: 32 k x 128 n, staged k-major per column (aligned 16B LDS
        // writes, no transpose scatter). Global: 2 x 128B segments per instr.
        {
            const int wcol = t >> 1, wk0 = (t & 1) * 16;
            const float* wp = &W[(size_t)(k0 + wk0) * Nd + h * HD + wcol];
            alignas(16) unsigned short hh[16];
            alignas(16) unsigned short ll[16];
#pragma unroll
            for (int uu = 0; uu < 16; uu++) {
                const float x = wp[(size_t)uu * Nd];
                hh[uu] = f2b(x);
                ll[uu] = f2b(x - b2f(hh[uu]));
            }
            *(uint4*)&pWh[wcol][wk0 + 0] = *(const uint4*)&hh[0];
            *(uint4*)&pWh[wcol][wk0 + 8] = *(const uint4*)&hh[8];
            if (np3) {
                *(uint4*)&pWl[wcol][wk0 + 0] = *(const uint4*)&ll[0];
                *(uint4*)&pWl[wcol][wk0 + 8] = *(const uint4*)&ll[8];
            }
        }
        __syncthreads();
        // fragments: A[row=lm][k=lq*8+j], B[col=lm][k=lq*8+j]
        short8 ah[2], al[2];
#pragma unroll
        for (int mt = 0; mt < 2; mt++) {
            ah[mt] = *(const short8*)&pAh[w * 32 + mt * 16 + lm][lq * 8];
            if (np3) al[mt] = *(const short8*)&pAl[w * 32 + mt * 16 + lm][lq * 8];
        }
#pragma unroll
        for (int nt = 0; nt < 8; nt++) {
            const short8 bh = *(const short8*)&pWh[nt * 16 + lm][lq * 8];
#pragma unroll
            for (int mt = 0; mt < 2; mt++)
                acc[mt][nt] = __builtin_amdgcn_mfma_f32_16x16x32_bf16(ah[mt], bh, acc[mt][nt], 0, 0, 0);
            if (np3) {
                const short8 bl = *(const short8*)&pWl[nt * 16 + lm][lq * 8];
#pragma unroll
                for (int mt = 0; mt < 2; mt++) {
                    acc[mt][nt] = __builtin_amdgcn_mfma_f32_16x16x32_bf16(ah[mt], bl, acc[mt][nt], 0, 0, 0);
                    acc[mt][nt] = __builtin_amdgcn_mfma_f32_16x16x32_bf16(al[mt], bh, acc[mt][nt], 0, 0, 0);
                }
            }
        }
    }

    // ---- RoPE (register-only; partner col^64 = tile nt^4, same lane) ----
    if (np3) {
        float invf[4];
#pragma unroll
        for (int c4 = 0; c4 < 4; c4++) {
            const int jj = c4 * 16 + lm;              // col & 63
            invf[c4] = 1.0f / powf(10000.0f, (float)jj * (1.0f / 64.0f));
        }
#pragma unroll
        for (int mt = 0; mt < 2; mt++) {
            const int rbase = w * 32 + mt * 16 + lq * 4;
#pragma unroll
            for (int rr = 0; rr < 4; rr++) {
                const float p = (float)pos_ids[m0g + rbase + rr];
#pragma unroll
                for (int c4 = 0; c4 < 4; c4++) {
                    const float fr = p * invf[c4];
                    float sv, cv;
                    sincosf(fr, &sv, &cv);
                    const float x1 = acc[mt][c4][rr];      // col < 64
                    const float x2 = acc[mt][c4 + 4][rr];  // col + 64
                    acc[mt][c4][rr]     = x1 * cv - x2 * sv;
                    acc[mt][c4 + 4][rr] = x2 * cv + x1 * sv;
                }
            }
        }
    }

    // ---- bf16 store + per-column row-sums for the sketch ----
    float cs[8];
#pragma unroll
    for (int nt = 0; nt < 8; nt++) cs[nt] = 0.f;
#pragma unroll
    for (int mt = 0; mt < 2; mt++) {
        const int rbase = w * 32 + mt * 16 + lq * 4;
#pragma unroll
        for (int rr = 0; rr < 4; rr++) {
            bf16* dst = &Xout[(size_t)(m0x + rbase + rr) * Nd + h * HD + lm];
#pragma unroll
            for (int nt = 0; nt < 8; nt++) {
                const float v = acc[mt][nt][rr];
                dst[nt * 16] = __float2bfloat16(v);
                cs[nt] += v;
            }
        }
    }
    if (!np3) return;   // V blocks: no sketch
    // reduce across the 4 quads (rows) of the wave
#pragma unroll
    for (int nt = 0; nt < 8; nt++) {
        cs[nt] += __shfl_xor(cs[nt], 16);
        cs[nt] += __shfl_xor(cs[nt], 32);
    }
    if (lq == 0) {
#pragma unroll
        for (int nt = 0; nt < 8; nt++) red[w][nt * 16 + lm] = cs[nt];
    }
    __syncthreads();
    // Sketch matvec: S[b][m] = (1/64) * sum_d colsum_b[d] * H[d][m]
    if (t < 64) {
        const int b = t >> 5, m = t & 31;
        float s = 0.f;
        for (int d = 0; d < 128; d++)
            s += (red[b * 2][d] + red[b * 2 + 1][d]) * H[d * MSK + m];
        Sout[((size_t)h * NBLK + (m0g >> 6) + b) * MSK + m] = s * (1.0f / 64.0f);
    }
}

// ---------------------------------------------------------------------------
// MFMA bf16 GEMM: C[cRow0+m, n] = A[m,:] @ W[:,n]. 64x64 tile, 4 waves,
// mfma_f32_16x16x32_bf16. A fp32 (convert) or bf16 (direct); W fp32->bf16.
// ---------------------------------------------------------------------------
__device__ __forceinline__ void stage8(const float* p, unsigned short* dst) {
    const float4 a = *(const float4*)p;
    const float4 b = *(const float4*)(p + 4);
    ushort4 u0; u0.x = f2b(a.x); u0.y = f2b(a.y); u0.z = f2b(a.z); u0.w = f2b(a.w);
    ushort4 u1; u1.x = f2b(b.x); u1.y = f2b(b.y); u1.z = f2b(b.z); u1.w = f2b(b.w);
    *(ushort4*)dst = u0; *(ushort4*)(dst + 4) = u1;
}
__device__ __forceinline__ void stage8(const bf16* p, unsigned short* dst) {
    *(uint4*)dst = *(const uint4*)p;
}

template <typename AT, typename CT>
__global__ __launch_bounds__(256) void gemm_mfma(const AT* __restrict__ A,
                                                 const float* __restrict__ W,
                                                 CT* __restrict__ C,
                                                 int Ndim, int Kdim, int cRow0) {
    __shared__ unsigned short Al[64][40];   // [m][k], stride 80B (16B-aligned)
    __shared__ unsigned short Wl[64][40];   // [n][k] (transposed in staging)
    const int n0 = blockIdx.x * 64, m0 = blockIdx.y * 64;
    const int t = threadIdx.x;
    const int w = t >> 6, L = t & 63;
    const int lm = L & 15, lq = L >> 4;
    f32x4 acc[4];
#pragma unroll
    for (int nt = 0; nt < 4; nt++) acc[nt] = (f32x4){0.f, 0.f, 0.f, 0.f};

    for (int k0 = 0; k0 < Kdim; k0 += 32) {
        __syncthreads();
        {   // A: 64 rows x 32 k; thread -> (row = t>>2, 8-el chunk = t&3)
            int row = t >> 2, c8 = t & 3;
            stage8(&A[(size_t)(m0 + row) * Kdim + k0 + c8 * 8], &Al[row][c8 * 8]);
        }
        {   // W: 32 k x 64 n, transposed into Wl[n][k]
            int kk = t >> 3, n8 = (t & 7) * 8;
            const float4 a = *(const float4*)&W[(size_t)(k0 + kk) * Ndim + n0 + n8];
            const float4 b = *(const float4*)&W[(size_t)(k0 + kk) * Ndim + n0 + n8 + 4];
            Wl[n8 + 0][kk] = f2b(a.x); Wl[n8 + 1][kk] = f2b(a.y);
            Wl[n8 + 2][kk] = f2b(a.z); Wl[n8 + 3][kk] = f2b(a.w);
            Wl[n8 + 4][kk] = f2b(b.x); Wl[n8 + 5][kk] = f2b(b.y);
            Wl[n8 + 6][kk] = f2b(b.z); Wl[n8 + 7][kk] = f2b(b.w);
        }
        __syncthreads();
        short8 av = *(const short8*)&Al[w * 16 + lm][lq * 8];
#pragma unroll
        for (int nt = 0; nt < 4; nt++) {
            short8 bv = *(const short8*)&Wl[nt * 16 + lm][lq * 8];
            acc[nt] = __builtin_amdgcn_mfma_f32_16x16x32_bf16(av, bv, acc[nt], 0, 0, 0);
        }
    }
#pragma unroll
    for (int nt = 0; nt < 4; nt++)
#pragma unroll
        for (int r = 0; r < 4; r++) {
            int row = w * 16 + lq * 4 + r, col = nt * 16 + lm;
            stc(&C[(size_t)(cRow0 + m0 + row) * Ndim + n0 + col], acc[nt][r]);
        }
}

// ---------------------------------------------------------------------------
// Block scores + top-8 for q-blocks i = i0 + bx. Tie-break = lowest index.
// ---------------------------------------------------------------------------
__global__ __launch_bounds__(64) void topk_kernel(const float* __restrict__ Sq,
                                                  const float* __restrict__ Sk,
                                                  int* __restrict__ topk, int i0) {
    const int i = i0 + blockIdx.x, h = blockIdx.y, kv = h >> 2;
    const int j = threadIdx.x;
    __shared__ float vals[64];
    float v;
    if (j > i) v = NEGV;
    else if (j == i) v = 1e9f;
    else {
        v = 0.f;
        const float* sq = Sq + ((size_t)h * NBLK + i) * MSK;
        const float* sk = Sk + ((size_t)kv * NBLK + j) * MSK;
        for (int m = 0; m < MSK; m++) v += sq[m] * sk[m];
    }
    vals[j] = v;
    __syncthreads();
    if (j == 0) {
        for (int kk = 0; kk < KTOP; kk++) {
            float best = SENT; int bi = 0;
            for (int jj = 0; jj < 64; jj++)
                if (vals[jj] > best) { best = vals[jj]; bi = jj; }
            vals[bi] = SENT;
            topk[((size_t)h * NBLK + i) * KTOP + kk] = bi;
        }
    }
}

// ---------------------------------------------------------------------------
// Sparse attention, online softmax, rows [r0, r0+CHrows). q rows are
// (global - qbase) in qf. Writes attn_c chunk-local (rows - r0).
// ---------------------------------------------------------------------------
__global__ __launch_bounds__(256) void attn_kernel(const bf16* __restrict__ qf,
                                                   const bf16* __restrict__ kf,
                                                   const bf16* __restrict__ vf,
                                                   const int* __restrict__ topk,
                                                   bf16* __restrict__ attn_c,
                                                   int r0, int qbase) {
    const int qbg = (r0 >> 6) + blockIdx.x;
    const int h = blockIdx.y, half = blockIdx.z;
    const int kvh = h >> 2;
    const int t = threadIdx.x;
    const int r = t & 31, g = t >> 5;
    __shared__ float Qs[32][129];
    __shared__ float KVs[64][129];
    __shared__ float Ss[32][65];
    __shared__ float mL[32], lL[32], aL[32];
    const int qrow0 = qbg * 64 + half * 32;

#pragma unroll
    for (int i = 0; i < 2; i++) {   // 32x128 bf16 = 512 uint4
        int idx = t + i * 256;
        int rr = idx >> 4, c8 = idx & 15;
        uint4 raw = *(const uint4*)&qf[(size_t)(qrow0 - qbase + rr) * (NH * HD) + h * HD + c8 * 8];
        const unsigned short* pu = (const unsigned short*)&raw;
#pragma unroll
        for (int j = 0; j < 8; j++)
            Qs[rr][c8 * 8 + j] = b2f(pu[j]) * 0.08838834764831845f;
    }
    if (t < 32) { mL[t] = -1.0e30f; lL[t] = 0.f; }
    float O[16];
#pragma unroll
    for (int c = 0; c < 16; c++) O[c] = 0.f;
    const int c0 = g * 16;
    const int* sel = topk + ((size_t)h * NBLK + qbg) * KTOP;

    for (int kb = 0; kb < KTOP; kb++) {
        const int blk = sel[kb] & 63;
        __syncthreads();   // (A)
#pragma unroll
        for (int i = 0; i < 4; i++) {   // 64x128 bf16 = 1024 uint4
            int idx = t + i * 256;
            int rr = idx >> 4, c8 = idx & 15;
            uint4 raw = *(const uint4*)&kf[(size_t)(blk * 64 + rr) * (NKV * HD) + kvh * HD + c8 * 8];
            const unsigned short* pu = (const unsigned short*)&raw;
#pragma unroll
            for (int j = 0; j < 8; j++) KVs[rr][c8 * 8 + j] = b2f(pu[j]);
        }
        __syncthreads();   // (B)
        float sc[8];
#pragma unroll
        for (int jj = 0; jj < 8; jj++) sc[jj] = 0.f;
        for (int d = 0; d < 128; d++) {
            float qv = Qs[r][d];
#pragma unroll
            for (int jj = 0; jj < 8; jj++) sc[jj] += qv * KVs[g * 8 + jj][d];
        }
        const int qpos = qrow0 + r;
#pragma unroll
        for (int jj = 0; jj < 8; jj++) {
            int j = g * 8 + jj;
            int kpos = blk * 64 + j;
            Ss[r][j] = (kpos <= qpos) ? sc[jj] : NEGV;
        }
        __syncthreads();   // (C)
#pragma unroll
        for (int i = 0; i < 4; i++) {   // stage V over K
            int idx = t + i * 256;
            int rr = idx >> 4, c8 = idx & 15;
            uint4 raw = *(const uint4*)&vf[(size_t)(blk * 64 + rr) * (NKV * HD) + kvh * HD + c8 * 8];
            const unsigned short* pu = (const unsigned short*)&raw;
#pragma unroll
            for (int j = 0; j < 8; j++) KVs[rr][c8 * 8 + j] = b2f(pu[j]);
        }
        if (t < 32) {
            const int row = t;
            float mb = SENT;
            for (int j = 0; j < 64; j++) mb = fmaxf(mb, Ss[row][j]);
            float mnew = fmaxf(mL[row], mb);
            float al = expf(mL[row] - mnew);
            float sum = 0.f;
            for (int j = 0; j < 64; j++) {
                float p = expf(Ss[row][j] - mnew);
                Ss[row][j] = p;
                sum += p;
            }
            lL[row] = lL[row] * al + sum;
            mL[row] = mnew;
            aL[row] = al;
        }
        __syncthreads();   // (D)
        float al = aL[r];
#pragma unroll
        for (int c = 0; c < 16; c++) O[c] *= al;
        for (int j = 0; j < 64; j++) {
            float p = Ss[r][j];
#pragma unroll
            for (int c = 0; c < 16; c++) O[c] += p * KVs[j][c0 + c];
        }
    }
    float inv_l = 1.0f / lL[r];
    bf16* dst = &attn_c[(size_t)(qrow0 - r0 + r) * (NH * HD) + h * HD + c0];
#pragma unroll
    for (int c4 = 0; c4 < 4; c4++) {
        ushort4 u;
        u.x = f2b(O[c4 * 4 + 0] * inv_l); u.y = f2b(O[c4 * 4 + 1] * inv_l);
        u.z = f2b(O[c4 * 4 + 2] * inv_l); u.w = f2b(O[c4 * 4 + 3] * inv_l);
        *(ushort4*)&dst[c4 * 4] = u;
    }
}

// ---------------------------------------------------------------------------
extern "C" void kernel_launch(void* const* d_in, const int* in_sizes, int n_in,
                              void* d_out, int out_size, void* d_ws, size_t ws_size,
                              hipStream_t stream) {
    const void *p_hid, *p_pos, *p_wq, *p_wk, *p_wv, *p_wo, *p_h;
    if (in_sizes[0] == 4096 && in_sizes[1] == 1048576) {
        p_h = d_in[0]; p_wk = d_in[1]; p_wo = d_in[2]; p_wq = d_in[3];
        p_wv = d_in[4]; p_hid = d_in[5]; p_pos = d_in[6];
    } else {
        p_hid = d_in[0]; p_pos = d_in[1]; p_wq = d_in[2]; p_wk = d_in[3];
        p_wv = d_in[4]; p_wo = d_in[5]; p_h = d_in[6];
    }
    const float* hidden = (const float*)p_hid;
    const int* pos_ids  = (const int*)p_pos;
    const float* Wq = (const float*)p_wq;
    const float* Wk = (const float*)p_wk;
    const float* Wv = (const float*)p_wv;
    const float* Wo = (const float*)p_wo;
    const float* Hsk = (const float*)p_h;
    float* out = (float*)d_out;

    // ws layout (bytes): Sq 131072 | Sk 32768 | topk 32768 | kf 4M | vf 4M |
    //   full: qf 16.78M | attn_c 4M  (total 29,556,736)
    //   fallback (proven 10.68MB): q_c 1M | attn_c 1M
    char* base = (char*)d_ws;
    float* Sq    = (float*)base;
    float* Sk    = (float*)(base + 131072);
    int*   topkb = (int*)(base + 163840);
    bf16*  kf    = (bf16*)(base + 196608);
    bf16*  vf    = (bf16*)(base + 196608 + 4194304);
    bf16*  qbuf  = (bf16*)(base + 196608 + 8388608);
    const size_t FULL_NEED = 29556736;
    const bool full = (ws_size >= FULL_NEED);

    if (full) {
        bf16* attn_c = qbuf + (size_t)S_LEN * NH * HD;     // 4MB, CH=1024
        // Q+K+V projection, RoPE, sketch: ONE launch, 768 blocks (3/CU).
        proj_rope_sketch<<<dim3(24, S_LEN / 128), 256, 0, stream>>>(
            hidden, Wq, Wk, Wv, pos_ids, Hsk, qbuf, kf, vf, Sq, Sk, 0, 0, 0);
        topk_kernel<<<dim3(NBLK, NH), 64, 0, stream>>>(Sq, Sk, topkb, 0);
        for (int c = 0; c < 4; c++) {
            const int r0 = c * 1024;
            attn_kernel<<<dim3(16, NH, 2), 256, 0, stream>>>(
                qbuf, kf, vf, topkb, attn_c, r0, 0);
            gemm_mfma<bf16, float><<<dim3(HID / 64, 16), 256, 0, stream>>>(
                attn_c, Wo, out, HID, HID, r0);
        }
    } else {
        bf16* attn_c = qbuf + (size_t)256 * NH * HD;       // 1MB, CH=256
        // K+V full-S projection first (units 16..23)
        proj_rope_sketch<<<dim3(8, S_LEN / 128), 256, 0, stream>>>(
            hidden, Wq, Wk, Wv, pos_ids, Hsk, qbuf, kf, vf, Sq, Sk, 16, 0, 0);
        for (int c = 0; c < 16; c++) {
            const int r0 = c * 256;
            proj_rope_sketch<<<dim3(16, 2), 256, 0, stream>>>(
                hidden, Wq, Wk, Wv, pos_ids, Hsk, qbuf, kf, vf, Sq, Sk, 0, r0, r0);
            topk_kernel<<<dim3(4, NH), 64, 0, stream>>>(Sq, Sk, topkb, r0 >> 6);
            attn_kernel<<<dim3(4, NH, 2), 256, 0, stream>>>(
                qbuf, kf, vf, topkb, attn_c, r0, r0);
            gemm_mfma<bf16, float><<<dim3(HID / 64, 4), 256, 0, stream>>>(
                attn_c, Wo, out, HID, HID, r0);
        }
    }
}

// Round 3
// 559.601 us; speedup vs baseline: 3.1471x; 2.3655x over previous
//
#include <hip/hip_runtime.h>
#include <hip/hip_bf16.h>

// Problem constants (B=1)
#define S_LEN 4096
#define HID 2048
#define NH 16
#define NKV 4
#define HD 128        // D
#define MSK 32        // M (sketch dim)
#define KTOP 8
#define NBLK 64       // S/BLK
#define NEGV -1000000000.0f
#define SENT -3.0e38f

typedef __hip_bfloat16 bf16;
typedef __attribute__((ext_vector_type(8))) short short8;   // 8 bf16 (4 VGPR)
typedef __attribute__((ext_vector_type(4))) float f32x4;

// EMPIRICAL (R1-R11): inputs fp32, output fp32. Selection (sketch->topk) needs
// near-fp32 precision: bf16x3 emulation (hi*hi + hi*lo + lo*hi, fp32 accum).
// V path needs only plain-bf16 (1 product). R12: attention + out-GEMM moved to
// MFMA; V stored transposed (vfT[d][s]) for PV's B-operand; attn writes its
// output IN PLACE over qf (each block consumes its own Q slice first) -> one
// attn launch + one out-GEMM launch, no attn_c buffer.

__device__ __forceinline__ unsigned short f2b(float v) {
    __hip_bfloat16 h = __float2bfloat16(v);
    return *reinterpret_cast<unsigned short*>(&h);
}
__device__ __forceinline__ float b2f(unsigned short u) {
    return __bfloat162float(*reinterpret_cast<__hip_bfloat16*>(&u));
}

// ---------------------------------------------------------------------------
// FUSED Q/K/V projection + RoPE + block-sketch (MFMA bf16x3), one launch.
// blockIdx.x + u0 = unit: [0,16) Q head, [16,20) K head, [20,24) V head.
// One block = 128 rows x 128 cols, 4 waves x (32 rows x 128 cols).
// Q/K: 3 products + RoPE + sketch, row-major bf16 out.
// V: 1 product, TRANSPOSED bf16 out (vfT[h*HD+d][s]) via LDS transpose.
// ---------------------------------------------------------------------------
__global__ __launch_bounds__(256, 3) void proj_rope_sketch(
    const float* __restrict__ A, const float* __restrict__ Wq,
    const float* __restrict__ Wk, const float* __restrict__ Wv,
    const int* __restrict__ pos_ids, const float* __restrict__ H,
    bf16* __restrict__ qf, bf16* __restrict__ kf, bf16* __restrict__ vf,
    float* __restrict__ Sq, float* __restrict__ Sk,
    int u0, int r0, int xbase) {
    const int u = blockIdx.x + u0;
    const bool isQ = (u < 16);
    const bool isV = (u >= 20);
    const bool np3 = !isV;                 // Q/K: 3 products, V: 1
    const int h = isQ ? u : (isV ? (u - 20) : (u - 16));
    const float* __restrict__ W = isQ ? Wq : (isV ? Wv : Wk);
    const int Nd = isQ ? (NH * HD) : (NKV * HD);
    bf16* __restrict__ Xout = isQ ? qf : kf;
    float* __restrict__ Sout = isQ ? Sq : Sk;

    const int m0g = r0 + blockIdx.y * 128;     // global row base (128 rows)
    const int m0x = isQ ? (m0g - xbase) : m0g; // only qf is chunk-local
    const int t = threadIdx.x;
    const int w = t >> 6, L = t & 63;
    const int lm = L & 15, lq = L >> 4;

    // LDS: one 40KB arena aliased as 4x [128][40] (A hi/lo, W hi/lo) during
    // the GEMM, and as the 128x136 transpose pane for the V epilogue.
    __shared__ __align__(16) unsigned short shmem[4 * 128 * 40];
    __shared__ float red[4][128];
    unsigned short(*pAh)[40] = (unsigned short(*)[40])(shmem);
    unsigned short(*pAl)[40] = (unsigned short(*)[40])(shmem + 128 * 40);
    unsigned short(*pWh)[40] = (unsigned short(*)[40])(shmem + 2 * 128 * 40);
    unsigned short(*pWl)[40] = (unsigned short(*)[40])(shmem + 3 * 128 * 40);

    f32x4 acc[2][8];
#pragma unroll
    for (int mt = 0; mt < 2; mt++)
#pragma unroll
        for (int nt = 0; nt < 8; nt++) acc[mt][nt] = (f32x4){0.f, 0.f, 0.f, 0.f};

    for (int k0 = 0; k0 < HID; k0 += 32) {
        __syncthreads();
        // A tile: 128 rows x 32 k (float4 coalesced), split fp32 -> bf16 hi/lo
#pragma unroll
        for (int i = 0; i < 4; i++) {
            const int idx = t + i * 256;           // 1024 float4
            const int row = idx >> 3, f4 = idx & 7;
            const float4 v = *(const float4*)&A[(size_t)(m0g + row) * HID + k0 + f4 * 4];
            ushort4 uh;
            uh.x = f2b(v.x); uh.y = f2b(v.y); uh.z = f2b(v.z); uh.w = f2b(v.w);
            *(ushort4*)&pAh[row][f4 * 4] = uh;
            if (np3) {
                ushort4 ul;
                ul.x = f2b(v.x - b2f(uh.x)); ul.y = f2b(v.y - b2f(uh.y));
                ul.z = f2b(v.z - b2f(uh.z)); ul.w = f2b(v.w - b2f(uh.w));
                *(ushort4*)&pAl[row][f4 * 4] = ul;
            }
        }
        // W tile: 32 k x 128 n, staged k-major per column (aligned 16B LDS
        // writes, no transpose scatter).
        {
            const int wcol = t >> 1, wk0 = (t & 1) * 16;
            const float* wp = &W[(size_t)(k0 + wk0) * Nd + h * HD + wcol];
            alignas(16) unsigned short hh[16];
            alignas(16) unsigned short ll[16];
#pragma unroll
            for (int uu = 0; uu < 16; uu++) {
                const float x = wp[(size_t)uu * Nd];
                hh[uu] = f2b(x);
                ll[uu] = f2b(x - b2f(hh[uu]));
            }
            *(uint4*)&pWh[wcol][wk0 + 0] = *(const uint4*)&hh[0];
            *(uint4*)&pWh[wcol][wk0 + 8] = *(const uint4*)&hh[8];
            if (np3) {
                *(uint4*)&pWl[wcol][wk0 + 0] = *(const uint4*)&ll[0];
                *(uint4*)&pWl[wcol][wk0 + 8] = *(const uint4*)&ll[8];
            }
        }
        __syncthreads();
        // fragments: A[row=lm][k=lq*8+j], B[col=lm][k=lq*8+j]
        short8 ah[2], al[2];
#pragma unroll
        for (int mt = 0; mt < 2; mt++) {
            ah[mt] = *(const short8*)&pAh[w * 32 + mt * 16 + lm][lq * 8];
            if (np3) al[mt] = *(const short8*)&pAl[w * 32 + mt * 16 + lm][lq * 8];
        }
#pragma unroll
        for (int nt = 0; nt < 8; nt++) {
            const short8 bh = *(const short8*)&pWh[nt * 16 + lm][lq * 8];
#pragma unroll
            for (int mt = 0; mt < 2; mt++)
                acc[mt][nt] = __builtin_amdgcn_mfma_f32_16x16x32_bf16(ah[mt], bh, acc[mt][nt], 0, 0, 0);
            if (np3) {
                const short8 bl = *(const short8*)&pWl[nt * 16 + lm][lq * 8];
#pragma unroll
                for (int mt = 0; mt < 2; mt++) {
                    acc[mt][nt] = __builtin_amdgcn_mfma_f32_16x16x32_bf16(ah[mt], bl, acc[mt][nt], 0, 0, 0);
                    acc[mt][nt] = __builtin_amdgcn_mfma_f32_16x16x32_bf16(al[mt], bh, acc[mt][nt], 0, 0, 0);
                }
            }
        }
    }

    if (isV) {
        // ---- V epilogue: LDS transpose -> vfT[h*HD + d][m0g + s] ----
        __syncthreads();   // all GEMM LDS reads done; reuse arena
        unsigned short(*Tv)[136] = (unsigned short(*)[136])shmem;
#pragma unroll
        for (int mt = 0; mt < 2; mt++) {
            const int rb = w * 32 + mt * 16 + lq * 4;
#pragma unroll
            for (int rr = 0; rr < 4; rr++)
#pragma unroll
                for (int nt = 0; nt < 8; nt++)
                    Tv[nt * 16 + lm][rb + rr] = f2b(acc[mt][nt][rr]);
        }
        __syncthreads();
        const int col = t >> 1, rh = (t & 1) * 64;
        bf16* dst = &vf[((size_t)h * HD + col) * S_LEN + m0g + rh];
#pragma unroll
        for (int u2 = 0; u2 < 8; u2++)
            *(uint4*)&dst[u2 * 8] = *(const uint4*)&Tv[col][rh + u2 * 8];
        return;
    }

    // ---- RoPE (register-only; partner col^64 = tile nt^4, same lane) ----
    {
        float invf[4];
#pragma unroll
        for (int c4 = 0; c4 < 4; c4++) {
            const int jj = c4 * 16 + lm;              // col & 63
            invf[c4] = 1.0f / powf(10000.0f, (float)jj * (1.0f / 64.0f));
        }
#pragma unroll
        for (int mt = 0; mt < 2; mt++) {
            const int rbase = w * 32 + mt * 16 + lq * 4;
#pragma unroll
            for (int rr = 0; rr < 4; rr++) {
                const float p = (float)pos_ids[m0g + rbase + rr];
#pragma unroll
                for (int c4 = 0; c4 < 4; c4++) {
                    const float fr = p * invf[c4];
                    float sv, cv;
                    sincosf(fr, &sv, &cv);
                    const float x1 = acc[mt][c4][rr];      // col < 64
                    const float x2 = acc[mt][c4 + 4][rr];  // col + 64
                    acc[mt][c4][rr]     = x1 * cv - x2 * sv;
                    acc[mt][c4 + 4][rr] = x2 * cv + x1 * sv;
                }
            }
        }
    }

    // ---- bf16 store + per-column row-sums for the sketch ----
    float cs[8];
#pragma unroll
    for (int nt = 0; nt < 8; nt++) cs[nt] = 0.f;
#pragma unroll
    for (int mt = 0; mt < 2; mt++) {
        const int rbase = w * 32 + mt * 16 + lq * 4;
#pragma unroll
        for (int rr = 0; rr < 4; rr++) {
            bf16* dst = &Xout[(size_t)(m0x + rbase + rr) * Nd + h * HD + lm];
#pragma unroll
            for (int nt = 0; nt < 8; nt++) {
                const float v = acc[mt][nt][rr];
                dst[nt * 16] = __float2bfloat16(v);
                cs[nt] += v;
            }
        }
    }
    // reduce across the 4 quads (rows) of the wave
#pragma unroll
    for (int nt = 0; nt < 8; nt++) {
        cs[nt] += __shfl_xor(cs[nt], 16);
        cs[nt] += __shfl_xor(cs[nt], 32);
    }
    if (lq == 0) {
#pragma unroll
        for (int nt = 0; nt < 8; nt++) red[w][nt * 16 + lm] = cs[nt];
    }
    __syncthreads();
    // Sketch matvec: S[b][m] = (1/64) * sum_d colsum_b[d] * H[d][m]
    if (t < 64) {
        const int b = t >> 5, m = t & 31;
        float s = 0.f;
        for (int d = 0; d < 128; d++)
            s += (red[b * 2][d] + red[b * 2 + 1][d]) * H[d * MSK + m];
        Sout[((size_t)h * NBLK + (m0g >> 6) + b) * MSK + m] = s * (1.0f / 64.0f);
    }
}

// ---------------------------------------------------------------------------
// Block scores + top-8 for q-blocks i = i0 + bx. Tie-break = lowest index.
// ---------------------------------------------------------------------------
__global__ __launch_bounds__(64) void topk_kernel(const float* __restrict__ Sq,
                                                  const float* __restrict__ Sk,
                                                  int* __restrict__ topk, int i0) {
    const int i = i0 + blockIdx.x, h = blockIdx.y, kv = h >> 2;
    const int j = threadIdx.x;
    __shared__ float vals[64];
    float v;
    if (j > i) v = NEGV;
    else if (j == i) v = 1e9f;
    else {
        v = 0.f;
        const float* sq = Sq + ((size_t)h * NBLK + i) * MSK;
        const float* sk = Sk + ((size_t)kv * NBLK + j) * MSK;
        for (int m = 0; m < MSK; m++) v += sq[m] * sk[m];
    }
    vals[j] = v;
    __syncthreads();
    if (j == 0) {
        for (int kk = 0; kk < KTOP; kk++) {
            float best = SENT; int bi = 0;
            for (int jj = 0; jj < 64; jj++)
                if (vals[jj] > best) { best = vals[jj]; bi = jj; }
            vals[bi] = SENT;
            topk[((size_t)h * NBLK + i) * KTOP + kk] = bi;
        }
    }
}

// ---------------------------------------------------------------------------
// MFMA sparse attention, online softmax in D-fragment registers.
// Block = 64 q-rows x head h; 4 waves x 16 q-rows. Writes output IN PLACE
// over qf (block reads only its own Q slice, fully, before writing).
// Layouts (proven): A[m=lm][k=lq*8+j], B[n=lm][k=lq*8+j], D col=lm,row=lq*4+r.
// ---------------------------------------------------------------------------
__global__ __launch_bounds__(256) void attn_kernel(bf16* __restrict__ qf,
                                                   const bf16* __restrict__ kf,
                                                   const bf16* __restrict__ vfT,
                                                   const int* __restrict__ topk,
                                                   int r0, int qbase) {
    const int qbg = (r0 >> 6) + blockIdx.x;
    const int h = blockIdx.y, kvh = h >> 2;
    const int t = threadIdx.x;
    const int w = t >> 6, L = t & 63;
    const int lm = L & 15, lq = L >> 4;

    __shared__ __align__(16) unsigned short Ks[64][136];   // [kcol][d]
    __shared__ __align__(16) unsigned short Vt[128][72];   // [d][kcol]
    __shared__ __align__(16) unsigned short Ps[64][72];    // [qrow][kcol]

    // Q fragments (registers, loaded once): rows qbg*64 + w*16 + lm
    short8 qfrag[4];
    {
        const size_t qrow = (size_t)(qbg * 64 - qbase) + w * 16 + lm;
        const unsigned short* qp = (const unsigned short*)qf + qrow * (NH * HD) + h * HD;
#pragma unroll
        for (int ks = 0; ks < 4; ks++)
            qfrag[ks] = *(const short8*)&qp[ks * 32 + lq * 8];
    }
    f32x4 O[8];
#pragma unroll
    for (int nt = 0; nt < 8; nt++) O[nt] = (f32x4){0.f, 0.f, 0.f, 0.f};
    f32x4 mrow = (f32x4){-1e30f, -1e30f, -1e30f, -1e30f};
    f32x4 lrow = (f32x4){0.f, 0.f, 0.f, 0.f};

    const int* sel = topk + ((size_t)h * NBLK + qbg) * KTOP;
    const int qpos0 = qbg * 64 + w * 16 + lq * 4;   // + r
    const float scale = 0.08838834764831845f;

    for (int kb = 0; kb < KTOP; kb++) {
        const int blk = sel[kb] & 63;
        __syncthreads();   // previous iteration's LDS reads done
        // stage K tile 64x128 (row-major, direct bf16 copy)
#pragma unroll
        for (int i = 0; i < 4; i++) {
            const int idx = t + i * 256;
            const int rr = idx >> 4, c8 = idx & 15;
            *(uint4*)&Ks[rr][c8 * 8] =
                *(const uint4*)&kf[(size_t)(blk * 64 + rr) * (NKV * HD) + kvh * HD + c8 * 8];
        }
        // stage V^T tile 128x64 (row-major in vfT, direct copy)
#pragma unroll
        for (int i = 0; i < 4; i++) {
            const int idx = t + i * 256;
            const int dd = idx >> 3, j8 = idx & 7;
            *(uint4*)&Vt[dd][j8 * 8] =
                *(const uint4*)&vfT[((size_t)kvh * HD + dd) * S_LEN + blk * 64 + j8 * 8];
        }
        __syncthreads();
        // S = Q @ K^T : D[m=qrow(16)][n=kcol(64)]
        f32x4 S4[4];
#pragma unroll
        for (int nt = 0; nt < 4; nt++) {
            S4[nt] = (f32x4){0.f, 0.f, 0.f, 0.f};
#pragma unroll
            for (int ks = 0; ks < 4; ks++) {
                const short8 bk = *(const short8*)&Ks[nt * 16 + lm][ks * 32 + lq * 8];
                S4[nt] = __builtin_amdgcn_mfma_f32_16x16x32_bf16(qfrag[ks], bk, S4[nt], 0, 0, 0);
            }
        }
        // scale + causal mask
#pragma unroll
        for (int nt = 0; nt < 4; nt++) {
            const int kpos = blk * 64 + nt * 16 + lm;
#pragma unroll
            for (int r = 0; r < 4; r++)
                S4[nt][r] = (kpos <= qpos0 + r) ? S4[nt][r] * scale : NEGV;
        }
        // row max over (nt, lm): lm lanes are bits 0-3
        f32x4 mx = S4[0];
#pragma unroll
        for (int nt = 1; nt < 4; nt++)
#pragma unroll
            for (int r = 0; r < 4; r++) mx[r] = fmaxf(mx[r], S4[nt][r]);
#pragma unroll
        for (int d = 1; d < 16; d <<= 1)
#pragma unroll
            for (int r = 0; r < 4; r++) mx[r] = fmaxf(mx[r], __shfl_xor(mx[r], d));
        f32x4 mnew, alv, sum;
#pragma unroll
        for (int r = 0; r < 4; r++) {
            mnew[r] = fmaxf(mrow[r], mx[r]);
            alv[r] = __expf(mrow[r] - mnew[r]);
            sum[r] = 0.f;
        }
#pragma unroll
        for (int nt = 0; nt < 4; nt++)
#pragma unroll
            for (int r = 0; r < 4; r++) {
                const float p = __expf(S4[nt][r] - mnew[r]);
                S4[nt][r] = p;
                sum[r] += p;
            }
#pragma unroll
        for (int d = 1; d < 16; d <<= 1)
#pragma unroll
            for (int r = 0; r < 4; r++) sum[r] += __shfl_xor(sum[r], d);
#pragma unroll
        for (int r = 0; r < 4; r++) {
            lrow[r] = lrow[r] * alv[r] + sum[r];
            mrow[r] = mnew[r];
        }
        // P -> bf16 into Ps (wave-private rows; no barrier needed)
#pragma unroll
        for (int nt = 0; nt < 4; nt++)
#pragma unroll
            for (int r = 0; r < 4; r++)
                Ps[w * 16 + lq * 4 + r][nt * 16 + lm] = f2b(S4[nt][r]);
        // O rescale + PV: O[16 x 128] += P[16 x 64] @ V[64 x 128]
#pragma unroll
        for (int nt = 0; nt < 8; nt++)
#pragma unroll
            for (int r = 0; r < 4; r++) O[nt][r] *= alv[r];
#pragma unroll
        for (int ks2 = 0; ks2 < 2; ks2++) {
            const short8 pa = *(const short8*)&Ps[w * 16 + lm][ks2 * 32 + lq * 8];
#pragma unroll
            for (int nt = 0; nt < 8; nt++) {
                const short8 vv = *(const short8*)&Vt[nt * 16 + lm][ks2 * 32 + lq * 8];
                O[nt] = __builtin_amdgcn_mfma_f32_16x16x32_bf16(pa, vv, O[nt], 0, 0, 0);
            }
        }
    }
    // normalize + in-place store over qf
    f32x4 inv;
#pragma unroll
    for (int r = 0; r < 4; r++) inv[r] = 1.0f / lrow[r];
    const size_t orow0 = (size_t)(qbg * 64 - qbase) + w * 16 + lq * 4;
#pragma unroll
    for (int nt = 0; nt < 8; nt++)
#pragma unroll
        for (int r = 0; r < 4; r++)
            qf[(orow0 + r) * (NH * HD) + h * HD + nt * 16 + lm] =
                __float2bfloat16(O[nt][r] * inv[r]);
}

// ---------------------------------------------------------------------------
// Output GEMM: C[cRow0+m, n] = A[m,:] @ Wo[:,n], 128x128 tile, 4 waves.
// A bf16 direct per-lane fragment loads (no LDS); W k-major staged with
// register prefetch (T14 split).
// ---------------------------------------------------------------------------
__global__ __launch_bounds__(256) void gemm_out(const bf16* __restrict__ A,
                                                const float* __restrict__ W,
                                                float* __restrict__ C, int cRow0) {
    __shared__ __align__(16) unsigned short Wl[128][40];
    const int n0 = blockIdx.x * 128, m0 = blockIdx.y * 128;
    const int t = threadIdx.x;
    const int w = t >> 6, L = t & 63;
    const int lm = L & 15, lq = L >> 4;
    const int wcol = t >> 1, wk0 = (t & 1) * 16;
    f32x4 acc[2][8];
#pragma unroll
    for (int mt = 0; mt < 2; mt++)
#pragma unroll
        for (int nt = 0; nt < 8; nt++) acc[mt][nt] = (f32x4){0.f, 0.f, 0.f, 0.f};

    float wreg[16];
    {
        const float* wp = &W[(size_t)wk0 * HID + n0 + wcol];
#pragma unroll
        for (int u = 0; u < 16; u++) wreg[u] = wp[(size_t)u * HID];
    }
    short8 av[2];
#pragma unroll
    for (int mt = 0; mt < 2; mt++)
        av[mt] = *(const short8*)&A[(size_t)(m0 + w * 32 + mt * 16 + lm) * HID + lq * 8];

    for (int k0 = 0; k0 < HID; k0 += 32) {
        __syncthreads();          // previous Wl reads done
        {
            alignas(16) unsigned short hh[16];
#pragma unroll
            for (int u = 0; u < 16; u++) hh[u] = f2b(wreg[u]);
            *(uint4*)&Wl[wcol][wk0 + 0] = *(const uint4*)&hh[0];
            *(uint4*)&Wl[wcol][wk0 + 8] = *(const uint4*)&hh[8];
        }
        const int k1 = k0 + 32;
        if (k1 < HID) {           // prefetch next W into regs (T14 split)
            const float* wp = &W[(size_t)(k1 + wk0) * HID + n0 + wcol];
#pragma unroll
            for (int u = 0; u < 16; u++) wreg[u] = wp[(size_t)u * HID];
        }
        __syncthreads();          // Wl ready
        short8 avn[2];
        if (k1 < HID) {           // prefetch next A frags
#pragma unroll
            for (int mt = 0; mt < 2; mt++)
                avn[mt] = *(const short8*)&A[(size_t)(m0 + w * 32 + mt * 16 + lm) * HID + k1 + lq * 8];
        }
#pragma unroll
        for (int nt = 0; nt < 8; nt++) {
            const short8 bv = *(const short8*)&Wl[nt * 16 + lm][lq * 8];
#pragma unroll
            for (int mt = 0; mt < 2; mt++)
                acc[mt][nt] = __builtin_amdgcn_mfma_f32_16x16x32_bf16(av[mt], bv, acc[mt][nt], 0, 0, 0);
        }
        if (k1 < HID) { av[0] = avn[0]; av[1] = avn[1]; }
    }
#pragma unroll
    for (int mt = 0; mt < 2; mt++)
#pragma unroll
        for (int nt = 0; nt < 8; nt++)
#pragma unroll
            for (int r = 0; r < 4; r++) {
                const int row = m0 + w * 32 + mt * 16 + lq * 4 + r;
                C[(size_t)(cRow0 + row) * HID + n0 + nt * 16 + lm] = acc[mt][nt][r];
            }
}

// ---------------------------------------------------------------------------
extern "C" void kernel_launch(void* const* d_in, const int* in_sizes, int n_in,
                              void* d_out, int out_size, void* d_ws, size_t ws_size,
                              hipStream_t stream) {
    const void *p_hid, *p_pos, *p_wq, *p_wk, *p_wv, *p_wo, *p_h;
    if (in_sizes[0] == 4096 && in_sizes[1] == 1048576) {
        p_h = d_in[0]; p_wk = d_in[1]; p_wo = d_in[2]; p_wq = d_in[3];
        p_wv = d_in[4]; p_hid = d_in[5]; p_pos = d_in[6];
    } else {
        p_hid = d_in[0]; p_pos = d_in[1]; p_wq = d_in[2]; p_wk = d_in[3];
        p_wv = d_in[4]; p_wo = d_in[5]; p_h = d_in[6];
    }
    const float* hidden = (const float*)p_hid;
    const int* pos_ids  = (const int*)p_pos;
    const float* Wq = (const float*)p_wq;
    const float* Wk = (const float*)p_wk;
    const float* Wv = (const float*)p_wv;
    const float* Wo = (const float*)p_wo;
    const float* Hsk = (const float*)p_h;
    float* out = (float*)d_out;

    // ws layout (bytes): Sq 131072 | Sk 32768 | topk 32768 | kf 4M | vfT 4M |
    //   full: qf 16.78M (attn output written in place)   total 25,362,432
    //   fallback: qf chunk 1M
    char* base = (char*)d_ws;
    float* Sq    = (float*)base;
    float* Sk    = (float*)(base + 131072);
    int*   topkb = (int*)(base + 163840);
    bf16*  kf    = (bf16*)(base + 196608);
    bf16*  vfT   = (bf16*)(base + 196608 + 4194304);
    bf16*  qbuf  = (bf16*)(base + 196608 + 8388608);
    const size_t FULL_NEED = 25362432;
    const bool full = (ws_size >= FULL_NEED);

    if (full) {
        // Q+K+V projection, RoPE, sketch: ONE launch, 768 blocks (3/CU).
        proj_rope_sketch<<<dim3(24, S_LEN / 128), 256, 0, stream>>>(
            hidden, Wq, Wk, Wv, pos_ids, Hsk, qbuf, kf, vfT, Sq, Sk, 0, 0, 0);
        topk_kernel<<<dim3(NBLK, NH), 64, 0, stream>>>(Sq, Sk, topkb, 0);
        attn_kernel<<<dim3(NBLK, NH), 256, 0, stream>>>(
            qbuf, kf, vfT, topkb, 0, 0);
        gemm_out<<<dim3(HID / 128, S_LEN / 128), 256, 0, stream>>>(
            qbuf, Wo, out, 0);
    } else {
        // K+V full-S projection first (units 16..23)
        proj_rope_sketch<<<dim3(8, S_LEN / 128), 256, 0, stream>>>(
            hidden, Wq, Wk, Wv, pos_ids, Hsk, qbuf, kf, vfT, Sq, Sk, 16, 0, 0);
        for (int c = 0; c < 16; c++) {
            const int r0 = c * 256;
            proj_rope_sketch<<<dim3(16, 2), 256, 0, stream>>>(
                hidden, Wq, Wk, Wv, pos_ids, Hsk, qbuf, kf, vfT, Sq, Sk, 0, r0, r0);
            topk_kernel<<<dim3(4, NH), 64, 0, stream>>>(Sq, Sk, topkb, r0 >> 6);
            attn_kernel<<<dim3(4, NH), 256, 0, stream>>>(
                qbuf, kf, vfT, topkb, r0, r0);
            gemm_out<<<dim3(HID / 128, 2), 256, 0, stream>>>(
                qbuf, Wo, out, r0);
        }
    }
}